// Round 5
// baseline (334.762 us; speedup 1.0000x reference)
//
#include <hip/hip_runtime.h>
#include <math.h>

// Problem constants: token shape (b=16, c=16, n=25, h=16, w=128)
#define SB 819200   // batch stride = c*n*h*w
#define SC 51200    // c stride    = n*h*w
#define SN 2048     // n stride    = h*w
#define CH 256      // c*h  (t dim)
#define NW 3200     // n*w  (k dim of gemm1, s dim of gemm2)
#define NPARTS 20
#define PARTLEN 160         // 3200 / 20
#define NSTEP 5             // PARTLEN / 32 K-steps
#define SPART 1048576       // 16*256*256 bf16 ELEMENTS per split-K partial (2 MB)
#define G1BLOCKS 960        // 3 tiles * 20 parts * 16 b

typedef __bf16 bf16x8 __attribute__((ext_vector_type(8)));
typedef __bf16 bf16x4 __attribute__((ext_vector_type(4)));
typedef __bf16 bf16x2 __attribute__((ext_vector_type(2)));
typedef float  f32x4  __attribute__((ext_vector_type(4)));

__device__ __forceinline__ bf16x8 cvt8(float4 a, float4 b) {
    bf16x8 r;
    r[0] = (__bf16)a.x; r[1] = (__bf16)a.y; r[2] = (__bf16)a.z; r[3] = (__bf16)a.w;
    r[4] = (__bf16)b.x; r[5] = (__bf16)b.y; r[6] = (__bf16)b.z; r[7] = (__bf16)b.w;
    return r;
}

__device__ __forceinline__ float dot4(float4 a) {
    return a.x * a.x + a.y * a.y + a.z * a.z + a.w * a.w;
}

// ---------------------------------------------------------------------------
// Kernel 1: split-K bf16-MFMA score GEMM + fused row sum-of-squares.
// Spart[p][b][t][r] = sum_{k in part p} Q[t][k]*K[r][k], stored BF16.
// 128x128 tile, 4 waves of 64x64, causal 3-tile, LDS-free fragment loads
// (per lane an MFMA A/B fragment = 8 contiguous k-floats of one row ->
// 2x dwordx4 direct from global, same pattern as gemm2's P-path).
// ROUND-5 CHANGE: occupancy. r2-r4 showed three different structures all
// stuck at ~52 us / 2 TB/s / 14% occupancy -- the invariant was 480 blocks
// at launch_bounds(256,2) = ~4.5 waves/CU, i.e. wave-level latency
// serialization. NPARTS 10->20 + bf16 Spart: 960 blocks (15 waves/CU
// potential) at launch_bounds(256,4), with total HBM bytes FLAT (bf16
// halves Spart: 20 parts x 2 MB = same softmax read, half the write).
// Norms: sumsq on the loaded f32 regs; wn==0 waves own A rows, wm==0
// waves own B rows; doQ/doK tile ownership keeps writes race-free.
// ---------------------------------------------------------------------------
__global__ __launch_bounds__(256, 4) void gemm1_kernel(const float* __restrict__ q,
                                                       const float* __restrict__ k,
                                                       __bf16* __restrict__ Sp,
                                                       float* __restrict__ nq2p,
                                                       float* __restrict__ nk2p) {
    const int tid = threadIdx.x;
    const int lane = tid & 63;
    const int wave = tid >> 6;
    const int l15 = lane & 15;
    const int quad = lane >> 4;

    const int bx = blockIdx.x;
    const int tile = bx % 3;               // 0:(0,0) 1:(1,0) 2:(1,1)
    const int part = (bx / 3) % NPARTS;
    const int b = bx / (3 * NPARTS);
    const int tm = (tile + 1) >> 1;
    const int tn = tile >> 1;

    const int wm = wave >> 1;              // m 64-half
    const int wn = wave & 1;               // n 64-half

    const bool doQ = (tile != 2);
    const bool doK = (tile != 1);

    // per-fragment row pointers (include quad's k-octet offset)
    const float* qrow[4];
    const float* krow[4];
#pragma unroll
    for (int i = 0; i < 4; i++) {
        const int ta = tm * 128 + wm * 64 + i * 16 + l15;
        const int rb = tn * 128 + wn * 64 + i * 16 + l15;
        qrow[i] = q + (size_t)b * SB + (size_t)(ta >> 4) * SC + (size_t)(ta & 15) * 128 + quad * 8;
        krow[i] = k + (size_t)b * SB + (size_t)(rb >> 4) * SC + (size_t)(rb & 15) * 128 + quad * 8;
    }

    f32x4 acc[4][4] = {};
    bool live[4][4];
#pragma unroll
    for (int mi = 0; mi < 4; mi++)
#pragma unroll
        for (int ni = 0; ni < 4; ni++)
            live[mi][ni] = (tn * 128 + wn * 64 + ni * 16) <= (tm * 128 + wm * 64 + mi * 16);

    float sqA[4] = {0.f, 0.f, 0.f, 0.f};
    float sqB[4] = {0.f, 0.f, 0.f, 0.f};

    // two in-flight register sets (static names -> no scratch, rule #20)
    float4 aL0[4], aH0[4], bL0[4], bH0[4];
    float4 aL1[4], aH1[4], bL1[4], bH1[4];

    // k-offset for step j: cols kgb..kgb+31; (kgb&127)+quad*8+7 <= 127,
    // never crosses the SN boundary.
    auto loadstep = [&](int j, float4* aL, float4* aH, float4* bL, float4* bH) {
        const int kgb = part * PARTLEN + j * 32;
        const size_t koff = (size_t)(kgb >> 7) * SN + (kgb & 127);
#pragma unroll
        for (int i = 0; i < 4; i++) {
            aL[i] = *(const float4*)(qrow[i] + koff);
            aH[i] = *(const float4*)(qrow[i] + koff + 4);
        }
#pragma unroll
        for (int i = 0; i < 4; i++) {
            bL[i] = *(const float4*)(krow[i] + koff);
            bH[i] = *(const float4*)(krow[i] + koff + 4);
        }
    };

    auto compute = [&](const float4* aL, const float4* aH,
                       const float4* bL, const float4* bH) {
        bf16x8 af[4], bfr[4];
#pragma unroll
        for (int mi = 0; mi < 4; mi++) {
            af[mi] = cvt8(aL[mi], aH[mi]);
            if (wn == 0) sqA[mi] += dot4(aL[mi]) + dot4(aH[mi]);
        }
#pragma unroll
        for (int ni = 0; ni < 4; ni++) {
            bfr[ni] = cvt8(bL[ni], bH[ni]);
            if (wm == 0) sqB[ni] += dot4(bL[ni]) + dot4(bH[ni]);
        }
#pragma unroll
        for (int mi = 0; mi < 4; mi++)
#pragma unroll
            for (int ni = 0; ni < 4; ni++)
                if (live[mi][ni])
                    acc[mi][ni] = __builtin_amdgcn_mfma_f32_16x16x32_bf16(
                        af[mi], bfr[ni], acc[mi][ni], 0, 0, 0);
    };

    // 5 steps: S0/S1 ping-pong, 1-step lookahead
    loadstep(0, aL0, aH0, bL0, bH0);
#pragma unroll
    for (int jj = 0; jj < 2; jj++) {
        loadstep(2 * jj + 1, aL1, aH1, bL1, bH1);
        __builtin_amdgcn_sched_barrier(0);      // loads issued before compute
        compute(aL0, aH0, bL0, bH0);            // step 2jj
        loadstep(2 * jj + 2, aL0, aH0, bL0, bH0);
        __builtin_amdgcn_sched_barrier(0);
        compute(aL1, aH1, bL1, bH1);            // step 2jj+1
    }
    compute(aL0, aH0, bL0, bH0);                // step 4

    // ---- Spart epilogue (bf16)
    __bf16* o = Sp + (size_t)part * SPART + (size_t)b * 65536;
#pragma unroll
    for (int mi = 0; mi < 4; mi++)
#pragma unroll
        for (int ni = 0; ni < 4; ni++) {
            if (!live[mi][ni]) continue;
            const int r = tn * 128 + wn * 64 + ni * 16 + l15;
#pragma unroll
            for (int j = 0; j < 4; j++) {
                const int t = tm * 128 + wm * 64 + mi * 16 + quad * 4 + j;
                o[(size_t)t * 256 + r] = (__bf16)acc[mi][ni][j];
            }
        }

    // ---- sumsq epilogue: reduce across the 4 quads (rows live in l15)
    if (wn == 0 && doQ) {
#pragma unroll
        for (int mi = 0; mi < 4; mi++) {
            float s = sqA[mi];
            s += __shfl_xor(s, 16, 64);
            s += __shfl_xor(s, 32, 64);
            if (lane < 16)
                nq2p[part * 4096 + b * 256 + tm * 128 + wm * 64 + mi * 16 + lane] = s;
        }
    }
    if (wm == 0 && doK) {
#pragma unroll
        for (int ni = 0; ni < 4; ni++) {
            float s = sqB[ni];
            s += __shfl_xor(s, 16, 64);
            s += __shfl_xor(s, 32, 64);
            if (lane < 16)
                nk2p[part * 4096 + b * 256 + tn * 128 + wn * 64 + ni * 16 + lane] = s;
        }
    }
}

// ---------------------------------------------------------------------------
// Kernel 2: sum bf16 split-K partials, finalize inverse norms from sumsq
// partials, causal mask, softmax, write P as bf16. One wave per (b,t) row.
// Dead regions of Spart are never written (garbage); masking overwrites
// val[] by assignment, so NaN/Inf garbage cannot propagate.
// ---------------------------------------------------------------------------
__global__ __launch_bounds__(256) void softmax_kernel(const __bf16* __restrict__ Sp,
                                                      const float* __restrict__ nq2p,
                                                      const float* __restrict__ nk2p,
                                                      __bf16* __restrict__ P) {
    const int wave = threadIdx.x >> 6;
    const int lane = threadIdx.x & 63;
    const int t = blockIdx.x * 4 + wave;
    const int b = blockIdx.y;
    const size_t rowbase = ((size_t)b * 256 + t) * 256;
    const int r0 = lane * 4;

    float s0 = 0.f, s1 = 0.f, s2 = 0.f, s3 = 0.f;
#pragma unroll
    for (int p = 0; p < NPARTS; p++) {
        const bf16x4 x = *(const bf16x4*)(Sp + (size_t)p * SPART + rowbase + r0);
        s0 += (float)x[0]; s1 += (float)x[1]; s2 += (float)x[2]; s3 += (float)x[3];
    }
    float sq = 0.f;
#pragma unroll
    for (int p = 0; p < NPARTS; p++) sq += nq2p[p * 4096 + b * 256 + t];
    float4 sk = {0.f, 0.f, 0.f, 0.f};
#pragma unroll
    for (int p = 0; p < NPARTS; p++) {
        const float4 x = *(const float4*)(nk2p + p * 4096 + b * 256 + r0);
        sk.x += x.x; sk.y += x.y; sk.z += x.z; sk.w += x.w;
    }
    const float qn = 1.0f / fmaxf(sqrtf(sq), 1e-12f);
    float4 kn;
    kn.x = 1.0f / fmaxf(sqrtf(sk.x), 1e-12f);
    kn.y = 1.0f / fmaxf(sqrtf(sk.y), 1e-12f);
    kn.z = 1.0f / fmaxf(sqrtf(sk.z), 1e-12f);
    kn.w = 1.0f / fmaxf(sqrtf(sk.w), 1e-12f);

    float val[4] = {s0 * qn * kn.x, s1 * qn * kn.y,
                    s2 * qn * kn.z, s3 * qn * kn.w};
    float m = -1e30f;
#pragma unroll
    for (int j = 0; j < 4; j++) {
        if (r0 + j > t) val[j] = -1e30f;
        m = fmaxf(m, val[j]);
    }
#pragma unroll
    for (int off = 32; off; off >>= 1) m = fmaxf(m, __shfl_xor(m, off, 64));

    float e[4], sum = 0.f;
#pragma unroll
    for (int j = 0; j < 4; j++) {
        e[j] = (r0 + j <= t) ? expf(val[j] - m) : 0.f;
        sum += e[j];
    }
#pragma unroll
    for (int off = 32; off; off >>= 1) sum += __shfl_xor(sum, off, 64);

    const float inv = 1.0f / sum;
    bf16x4 o;
    o[0] = (__bf16)(e[0] * inv);
    o[1] = (__bf16)(e[1] * inv);
    o[2] = (__bf16)(e[2] * inv);
    o[3] = (__bf16)(e[3] * inv);
    *(bf16x4*)(P + rowbase + r0) = o;
}

// ---------------------------------------------------------------------------
// Kernel 3: O[t][s] = sum_r P[t][r]*V[r][s] + V[t][s], bf16 MFMA.
// Block = 128 t x 64 s (half of one n), K = 256 r in 4 chunks of 64.
// P A-fragments load DIRECTLY from global (natural [t][r] layout == A-frag
// layout; P is 2 MB, L2-hot). Only V goes through LDS (transposed, paired-row
// b32 stores, XOR swizzle). grid (50 nw, 2 t-tiles, 16 b) = 1600 blocks.
// ---------------------------------------------------------------------------
__global__ __launch_bounds__(256, 4) void gemm2_kernel(const __bf16* __restrict__ P,
                                                       const float* __restrict__ v,
                                                       float* __restrict__ out) {
    __shared__ alignas(16) char smem[9216];
    __bf16* Vs = (__bf16*)smem;     // [64 s][72 r-stride]  (9216 B)
    float* Es = (float*)smem;       // [32][68] epilogue reuse (8704 B)

    const int tid = threadIdx.x;
    const int b = blockIdx.z;
    const int tt = blockIdx.y;      // 0..1 (t 128-half)
    const int nw = blockIdx.x;      // 0..49
    const int n = nw >> 1;
    const int whalf = nw & 1;

    const int lane = tid & 63;
    const int wave = tid >> 6;
    const int wm = wave >> 1;       // t 64-half within 128-tile
    const int wn = wave & 1;        // s 32-half within 64-tile
    const int l15 = lane & 15;
    const int quad = lane >> 4;

    // V staging coords: thread covers s-group vu*8..+7, row pair 2rp, 2rp+1
    const int vu = tid & 7;
    const int rp = tid >> 3;        // 0..31
    const float* vbase = v + (size_t)b * SB + (size_t)n * SN + whalf * 64;

    // P A-frag base: row = tt*128 + wm*64 + mi*16 + l15, col = kc*64+ks*32+quad*8
    const __bf16* Pbase = P + ((size_t)b * 256 + tt * 128 + wm * 64 + l15) * 256 + quad * 8;

    f32x4 acc[4][2] = {};

    for (int kc = 0; kc < 4; kc++) {
        // A fragments direct from global (issued early, L2-hot)
        bf16x8 af[4][2];
#pragma unroll
        for (int mi = 0; mi < 4; mi++)
#pragma unroll
            for (int ks = 0; ks < 2; ks++)
                af[mi][ks] = *(const bf16x8*)(Pbase + (size_t)mi * 16 * 256 + kc * 64 + ks * 32);

        // V loads: rows 2rp, 2rp+1 of this r-chunk, 8 floats each
        float vr0[8], vr1[8];
        {
            const int r0 = kc * 64 + 2 * rp;
            const int r1 = r0 + 1;
            const float* row0 = vbase + (size_t)(r0 >> 4) * SC + (size_t)(r0 & 15) * 128;
            const float* row1 = vbase + (size_t)(r1 >> 4) * SC + (size_t)(r1 & 15) * 128;
            *(float4*)&vr0[0] = *(const float4*)(row0 + vu * 8);
            *(float4*)&vr0[4] = *(const float4*)(row0 + vu * 8 + 4);
            *(float4*)&vr1[0] = *(const float4*)(row1 + vu * 8);
            *(float4*)&vr1[4] = *(const float4*)(row1 + vu * 8 + 4);
        }
        __syncthreads();   // prior Vs reads (or Es init) done
        {
            const int rl0 = 2 * rp;
#pragma unroll
            for (int sj = 0; sj < 8; sj++) {
                const int s = vu * 8 + sj;
                bf16x2 pr;
                pr[0] = (__bf16)vr0[sj];
                pr[1] = (__bf16)vr1[sj];
                *(bf16x2*)&Vs[s * 72 + (rl0 ^ (s & 0x38))] = pr;
            }
        }
        __syncthreads();
#pragma unroll
        for (int ks = 0; ks < 2; ks++) {
            bf16x8 bfr[2];
#pragma unroll
            for (int ni = 0; ni < 2; ni++) {
                const int s = wn * 32 + ni * 16 + l15;
                bfr[ni] = *(const bf16x8*)&Vs[s * 72 + ((ks * 32 + quad * 8) ^ (s & 0x38))];
            }
#pragma unroll
            for (int mi = 0; mi < 4; mi++)
#pragma unroll
                for (int ni = 0; ni < 2; ni++)
                    acc[mi][ni] = __builtin_amdgcn_mfma_f32_16x16x32_bf16(
                        af[mi][ks], bfr[ni], acc[mi][ni], 0, 0, 0);
        }
    }

    // ---- epilogue: 4 passes of 32 t-rows through Es[32][68], coalesced out
    for (int p = 0; p < 4; p++) {
        __syncthreads();   // prior Vs/Es reads done
        if (wm == (p >> 1)) {
            const int mibase = (p & 1) * 2;
#pragma unroll
            for (int mm = 0; mm < 2; mm++)
#pragma unroll
                for (int ni = 0; ni < 2; ni++) {
                    const f32x4 a = acc[mibase + mm][ni];
                    const int wcol = wn * 32 + ni * 16 + l15;
#pragma unroll
                    for (int j = 0; j < 4; j++)
                        Es[(mm * 16 + quad * 4 + j) * 68 + wcol] = a[j];
                }
        }
        __syncthreads();
#pragma unroll
        for (int it = 0; it < 2; it++) {
            const int tl = it * 16 + (tid >> 4);      // 0..31
            const int w4 = (tid & 15) * 4;            // 0..60
            const int t = tt * 128 + p * 32 + tl;
            const size_t a = (size_t)b * SB + (size_t)(t >> 4) * SC + (size_t)n * SN +
                             (size_t)(t & 15) * 128 + whalf * 64 + w4;
            float4 r4 = *(const float4*)&Es[tl * 68 + w4];
            const float4 buf = *(const float4*)(v + a);
            r4.x += buf.x; r4.y += buf.y; r4.z += buf.z; r4.w += buf.w;
            *(float4*)(out + a) = r4;
        }
    }
}

// ---------------------------------------------------------------------------
extern "C" void kernel_launch(void* const* d_in, const int* in_sizes, int n_in,
                              void* d_out, int out_size, void* d_ws, size_t ws_size,
                              hipStream_t stream) {
    const float* q = (const float*)d_in[0];
    const float* k = (const float*)d_in[1];
    const float* v = (const float*)d_in[2];
    float* out = (float*)d_out;

    float* ws = (float*)d_ws;
    float* nq2p = ws;                          // 20*4096 floats (sumsq partials)
    float* nk2p = ws + 81920;                  // 20*4096 floats
    __bf16* P = (__bf16*)(ws + 163840);        // 2 MB

    // d_out doubles as split-K scratch (20 * 2 MB bf16 = 40 MB <= 52 MB out),
    // fully overwritten by gemm2 afterwards.
    __bf16* Spart = (__bf16*)out;

    gemm1_kernel<<<dim3(G1BLOCKS), dim3(256), 0, stream>>>(q, k, Spart, nq2p, nk2p);
    softmax_kernel<<<dim3(64, 16), dim3(256), 0, stream>>>(Spart, nq2p, nk2p, P);
    gemm2_kernel<<<dim3(50, 2, 16), dim3(256), 0, stream>>>(P, v, out);
}

// Round 6
// 230.616 us; speedup vs baseline: 1.4516x; 1.4516x over previous
//
#include <hip/hip_runtime.h>
#include <math.h>

// Problem constants: token shape (b=16, c=16, n=25, h=16, w=128)
#define SB 819200   // batch stride = c*n*h*w
#define SC 51200    // c stride    = n*h*w
#define SN 2048     // n stride    = h*w
#define CH 256      // c*h  (t dim)
#define NW 3200     // n*w  (k dim of gemm1, s dim of gemm2)
#define NPARTS 20
#define PARTLEN 160         // 3200 / 20
#define NSTEP 5             // PARTLEN / 32 K-steps
#define SPART 1048576       // 16*256*256 bf16 ELEMENTS per split-K partial (2 MB)
#define G1BLOCKS 960        // 3 tiles * 20 parts * 16 b

typedef __bf16 bf16x8 __attribute__((ext_vector_type(8)));
typedef __bf16 bf16x4 __attribute__((ext_vector_type(4)));
typedef __bf16 bf16x2 __attribute__((ext_vector_type(2)));
typedef float  f32x4  __attribute__((ext_vector_type(4)));

__device__ __forceinline__ bf16x8 cvt8(float4 a, float4 b) {
    bf16x8 r;
    r[0] = (__bf16)a.x; r[1] = (__bf16)a.y; r[2] = (__bf16)a.z; r[3] = (__bf16)a.w;
    r[4] = (__bf16)b.x; r[5] = (__bf16)b.y; r[6] = (__bf16)b.z; r[7] = (__bf16)b.w;
    return r;
}

__device__ __forceinline__ float dot4(float4 a) {
    return a.x * a.x + a.y * a.y + a.z * a.z + a.w * a.w;
}

// ---------------------------------------------------------------------------
// Kernel 1: split-K bf16-MFMA score GEMM + fused row sum-of-squares.
// Spart[p][b][t][r] = sum_{k in part p} Q[t][k]*K[r][k], stored BF16.
// 128x128 tile, 4 waves of 64x64, causal 3-tile, LDS-free fragment loads
// (per lane an MFMA A/B fragment = 8 contiguous k-floats of one row ->
// 2x dwordx4 direct from global, same pattern as gemm2's P-path).
// ROUND-6: r5's launch_bounds(256,4) capped VGPR at 64 -> the prefetch
// sets spilled to scratch (WRITE 267 MB, FETCH 227 MB, 162 us). But r5
// also proved occupancy works: 38% resident sustained 3.1 TB/s. This
// round keeps the TLP (960 blocks, NPARTS=20, bf16 Spart = flat bytes)
// and restores launch_bounds(256,2): ~116 VGPR, no spill, HW fits
// 4 waves/SIMD -> ~3.75 blocks/CU resident.
// Norms: sumsq on the loaded f32 regs; wn==0 waves own A rows, wm==0
// waves own B rows; doQ/doK tile ownership keeps writes race-free.
// ---------------------------------------------------------------------------
__global__ __launch_bounds__(256, 2) void gemm1_kernel(const float* __restrict__ q,
                                                       const float* __restrict__ k,
                                                       __bf16* __restrict__ Sp,
                                                       float* __restrict__ nq2p,
                                                       float* __restrict__ nk2p) {
    const int tid = threadIdx.x;
    const int lane = tid & 63;
    const int wave = tid >> 6;
    const int l15 = lane & 15;
    const int quad = lane >> 4;

    const int bx = blockIdx.x;
    const int tile = bx % 3;               // 0:(0,0) 1:(1,0) 2:(1,1)
    const int part = (bx / 3) % NPARTS;
    const int b = bx / (3 * NPARTS);
    const int tm = (tile + 1) >> 1;
    const int tn = tile >> 1;

    const int wm = wave >> 1;              // m 64-half
    const int wn = wave & 1;               // n 64-half

    const bool doQ = (tile != 2);
    const bool doK = (tile != 1);

    // per-fragment row pointers (include quad's k-octet offset)
    const float* qrow[4];
    const float* krow[4];
#pragma unroll
    for (int i = 0; i < 4; i++) {
        const int ta = tm * 128 + wm * 64 + i * 16 + l15;
        const int rb = tn * 128 + wn * 64 + i * 16 + l15;
        qrow[i] = q + (size_t)b * SB + (size_t)(ta >> 4) * SC + (size_t)(ta & 15) * 128 + quad * 8;
        krow[i] = k + (size_t)b * SB + (size_t)(rb >> 4) * SC + (size_t)(rb & 15) * 128 + quad * 8;
    }

    f32x4 acc[4][4] = {};
    bool live[4][4];
#pragma unroll
    for (int mi = 0; mi < 4; mi++)
#pragma unroll
        for (int ni = 0; ni < 4; ni++)
            live[mi][ni] = (tn * 128 + wn * 64 + ni * 16) <= (tm * 128 + wm * 64 + mi * 16);

    float sqA[4] = {0.f, 0.f, 0.f, 0.f};
    float sqB[4] = {0.f, 0.f, 0.f, 0.f};

    // two in-flight register sets (static names -> no scratch, rule #20)
    float4 aL0[4], aH0[4], bL0[4], bH0[4];
    float4 aL1[4], aH1[4], bL1[4], bH1[4];

    // k-offset for step j: cols kgb..kgb+31; (kgb&127)+quad*8+7 <= 127,
    // never crosses the SN boundary.
    auto loadstep = [&](int j, float4* aL, float4* aH, float4* bL, float4* bH) {
        const int kgb = part * PARTLEN + j * 32;
        const size_t koff = (size_t)(kgb >> 7) * SN + (kgb & 127);
#pragma unroll
        for (int i = 0; i < 4; i++) {
            aL[i] = *(const float4*)(qrow[i] + koff);
            aH[i] = *(const float4*)(qrow[i] + koff + 4);
        }
#pragma unroll
        for (int i = 0; i < 4; i++) {
            bL[i] = *(const float4*)(krow[i] + koff);
            bH[i] = *(const float4*)(krow[i] + koff + 4);
        }
    };

    auto compute = [&](const float4* aL, const float4* aH,
                       const float4* bL, const float4* bH) {
        bf16x8 af[4], bfr[4];
#pragma unroll
        for (int mi = 0; mi < 4; mi++) {
            af[mi] = cvt8(aL[mi], aH[mi]);
            if (wn == 0) sqA[mi] += dot4(aL[mi]) + dot4(aH[mi]);
        }
#pragma unroll
        for (int ni = 0; ni < 4; ni++) {
            bfr[ni] = cvt8(bL[ni], bH[ni]);
            if (wm == 0) sqB[ni] += dot4(bL[ni]) + dot4(bH[ni]);
        }
#pragma unroll
        for (int mi = 0; mi < 4; mi++)
#pragma unroll
            for (int ni = 0; ni < 4; ni++)
                if (live[mi][ni])
                    acc[mi][ni] = __builtin_amdgcn_mfma_f32_16x16x32_bf16(
                        af[mi], bfr[ni], acc[mi][ni], 0, 0, 0);
    };

    // 5 steps: S0/S1 ping-pong, 1-step lookahead
    loadstep(0, aL0, aH0, bL0, bH0);
#pragma unroll
    for (int jj = 0; jj < 2; jj++) {
        loadstep(2 * jj + 1, aL1, aH1, bL1, bH1);
        __builtin_amdgcn_sched_barrier(0);      // loads issued before compute
        compute(aL0, aH0, bL0, bH0);            // step 2jj
        loadstep(2 * jj + 2, aL0, aH0, bL0, bH0);
        __builtin_amdgcn_sched_barrier(0);
        compute(aL1, aH1, bL1, bH1);            // step 2jj+1
    }
    compute(aL0, aH0, bL0, bH0);                // step 4

    // ---- Spart epilogue (bf16)
    __bf16* o = Sp + (size_t)part * SPART + (size_t)b * 65536;
#pragma unroll
    for (int mi = 0; mi < 4; mi++)
#pragma unroll
        for (int ni = 0; ni < 4; ni++) {
            if (!live[mi][ni]) continue;
            const int r = tn * 128 + wn * 64 + ni * 16 + l15;
#pragma unroll
            for (int j = 0; j < 4; j++) {
                const int t = tm * 128 + wm * 64 + mi * 16 + quad * 4 + j;
                o[(size_t)t * 256 + r] = (__bf16)acc[mi][ni][j];
            }
        }

    // ---- sumsq epilogue: reduce across the 4 quads (rows live in l15)
    if (wn == 0 && doQ) {
#pragma unroll
        for (int mi = 0; mi < 4; mi++) {
            float s = sqA[mi];
            s += __shfl_xor(s, 16, 64);
            s += __shfl_xor(s, 32, 64);
            if (lane < 16)
                nq2p[part * 4096 + b * 256 + tm * 128 + wm * 64 + mi * 16 + lane] = s;
        }
    }
    if (wm == 0 && doK) {
#pragma unroll
        for (int ni = 0; ni < 4; ni++) {
            float s = sqB[ni];
            s += __shfl_xor(s, 16, 64);
            s += __shfl_xor(s, 32, 64);
            if (lane < 16)
                nk2p[part * 4096 + b * 256 + tn * 128 + wn * 64 + ni * 16 + lane] = s;
        }
    }
}

// ---------------------------------------------------------------------------
// Kernel 2: sum bf16 split-K partials, finalize inverse norms from sumsq
// partials, causal mask, softmax, write P as bf16. One wave per (b,t) row.
// Dead regions of Spart are never written (garbage); masking overwrites
// val[] by assignment, so NaN/Inf garbage cannot propagate.
// ---------------------------------------------------------------------------
__global__ __launch_bounds__(256) void softmax_kernel(const __bf16* __restrict__ Sp,
                                                      const float* __restrict__ nq2p,
                                                      const float* __restrict__ nk2p,
                                                      __bf16* __restrict__ P) {
    const int wave = threadIdx.x >> 6;
    const int lane = threadIdx.x & 63;
    const int t = blockIdx.x * 4 + wave;
    const int b = blockIdx.y;
    const size_t rowbase = ((size_t)b * 256 + t) * 256;
    const int r0 = lane * 4;

    float s0 = 0.f, s1 = 0.f, s2 = 0.f, s3 = 0.f;
#pragma unroll
    for (int p = 0; p < NPARTS; p++) {
        const bf16x4 x = *(const bf16x4*)(Sp + (size_t)p * SPART + rowbase + r0);
        s0 += (float)x[0]; s1 += (float)x[1]; s2 += (float)x[2]; s3 += (float)x[3];
    }
    float sq = 0.f;
#pragma unroll
    for (int p = 0; p < NPARTS; p++) sq += nq2p[p * 4096 + b * 256 + t];
    float4 sk = {0.f, 0.f, 0.f, 0.f};
#pragma unroll
    for (int p = 0; p < NPARTS; p++) {
        const float4 x = *(const float4*)(nk2p + p * 4096 + b * 256 + r0);
        sk.x += x.x; sk.y += x.y; sk.z += x.z; sk.w += x.w;
    }
    const float qn = 1.0f / fmaxf(sqrtf(sq), 1e-12f);
    float4 kn;
    kn.x = 1.0f / fmaxf(sqrtf(sk.x), 1e-12f);
    kn.y = 1.0f / fmaxf(sqrtf(sk.y), 1e-12f);
    kn.z = 1.0f / fmaxf(sqrtf(sk.z), 1e-12f);
    kn.w = 1.0f / fmaxf(sqrtf(sk.w), 1e-12f);

    float val[4] = {s0 * qn * kn.x, s1 * qn * kn.y,
                    s2 * qn * kn.z, s3 * qn * kn.w};
    float m = -1e30f;
#pragma unroll
    for (int j = 0; j < 4; j++) {
        if (r0 + j > t) val[j] = -1e30f;
        m = fmaxf(m, val[j]);
    }
#pragma unroll
    for (int off = 32; off; off >>= 1) m = fmaxf(m, __shfl_xor(m, off, 64));

    float e[4], sum = 0.f;
#pragma unroll
    for (int j = 0; j < 4; j++) {
        e[j] = (r0 + j <= t) ? expf(val[j] - m) : 0.f;
        sum += e[j];
    }
#pragma unroll
    for (int off = 32; off; off >>= 1) sum += __shfl_xor(sum, off, 64);

    const float inv = 1.0f / sum;
    bf16x4 o;
    o[0] = (__bf16)(e[0] * inv);
    o[1] = (__bf16)(e[1] * inv);
    o[2] = (__bf16)(e[2] * inv);
    o[3] = (__bf16)(e[3] * inv);
    *(bf16x4*)(P + rowbase + r0) = o;
}

// ---------------------------------------------------------------------------
// Kernel 3: O[t][s] = sum_r P[t][r]*V[r][s] + V[t][s], bf16 MFMA.
// Block = 128 t x 64 s (half of one n), K = 256 r in 4 chunks of 64.
// P A-fragments load DIRECTLY from global (natural [t][r] layout == A-frag
// layout; P is 2 MB, L2-hot). Only V goes through LDS (transposed, paired-row
// b32 stores, XOR swizzle). grid (50 nw, 2 t-tiles, 16 b) = 1600 blocks.
// ---------------------------------------------------------------------------
__global__ __launch_bounds__(256, 4) void gemm2_kernel(const __bf16* __restrict__ P,
                                                       const float* __restrict__ v,
                                                       float* __restrict__ out) {
    __shared__ alignas(16) char smem[9216];
    __bf16* Vs = (__bf16*)smem;     // [64 s][72 r-stride]  (9216 B)
    float* Es = (float*)smem;       // [32][68] epilogue reuse (8704 B)

    const int tid = threadIdx.x;
    const int b = blockIdx.z;
    const int tt = blockIdx.y;      // 0..1 (t 128-half)
    const int nw = blockIdx.x;      // 0..49
    const int n = nw >> 1;
    const int whalf = nw & 1;

    const int lane = tid & 63;
    const int wave = tid >> 6;
    const int wm = wave >> 1;       // t 64-half within 128-tile
    const int wn = wave & 1;        // s 32-half within 64-tile
    const int l15 = lane & 15;
    const int quad = lane >> 4;

    // V staging coords: thread covers s-group vu*8..+7, row pair 2rp, 2rp+1
    const int vu = tid & 7;
    const int rp = tid >> 3;        // 0..31
    const float* vbase = v + (size_t)b * SB + (size_t)n * SN + whalf * 64;

    // P A-frag base: row = tt*128 + wm*64 + mi*16 + l15, col = kc*64+ks*32+quad*8
    const __bf16* Pbase = P + ((size_t)b * 256 + tt * 128 + wm * 64 + l15) * 256 + quad * 8;

    f32x4 acc[4][2] = {};

    for (int kc = 0; kc < 4; kc++) {
        // A fragments direct from global (issued early, L2-hot)
        bf16x8 af[4][2];
#pragma unroll
        for (int mi = 0; mi < 4; mi++)
#pragma unroll
            for (int ks = 0; ks < 2; ks++)
                af[mi][ks] = *(const bf16x8*)(Pbase + (size_t)mi * 16 * 256 + kc * 64 + ks * 32);

        // V loads: rows 2rp, 2rp+1 of this r-chunk, 8 floats each
        float vr0[8], vr1[8];
        {
            const int r0 = kc * 64 + 2 * rp;
            const int r1 = r0 + 1;
            const float* row0 = vbase + (size_t)(r0 >> 4) * SC + (size_t)(r0 & 15) * 128;
            const float* row1 = vbase + (size_t)(r1 >> 4) * SC + (size_t)(r1 & 15) * 128;
            *(float4*)&vr0[0] = *(const float4*)(row0 + vu * 8);
            *(float4*)&vr0[4] = *(const float4*)(row0 + vu * 8 + 4);
            *(float4*)&vr1[0] = *(const float4*)(row1 + vu * 8);
            *(float4*)&vr1[4] = *(const float4*)(row1 + vu * 8 + 4);
        }
        __syncthreads();   // prior Vs reads (or Es init) done
        {
            const int rl0 = 2 * rp;
#pragma unroll
            for (int sj = 0; sj < 8; sj++) {
                const int s = vu * 8 + sj;
                bf16x2 pr;
                pr[0] = (__bf16)vr0[sj];
                pr[1] = (__bf16)vr1[sj];
                *(bf16x2*)&Vs[s * 72 + (rl0 ^ (s & 0x38))] = pr;
            }
        }
        __syncthreads();
#pragma unroll
        for (int ks = 0; ks < 2; ks++) {
            bf16x8 bfr[2];
#pragma unroll
            for (int ni = 0; ni < 2; ni++) {
                const int s = wn * 32 + ni * 16 + l15;
                bfr[ni] = *(const bf16x8*)&Vs[s * 72 + ((ks * 32 + quad * 8) ^ (s & 0x38))];
            }
#pragma unroll
            for (int mi = 0; mi < 4; mi++)
#pragma unroll
                for (int ni = 0; ni < 2; ni++)
                    acc[mi][ni] = __builtin_amdgcn_mfma_f32_16x16x32_bf16(
                        af[mi][ks], bfr[ni], acc[mi][ni], 0, 0, 0);
        }
    }

    // ---- epilogue: 4 passes of 32 t-rows through Es[32][68], coalesced out
    for (int p = 0; p < 4; p++) {
        __syncthreads();   // prior Vs/Es reads done
        if (wm == (p >> 1)) {
            const int mibase = (p & 1) * 2;
#pragma unroll
            for (int mm = 0; mm < 2; mm++)
#pragma unroll
                for (int ni = 0; ni < 2; ni++) {
                    const f32x4 a = acc[mibase + mm][ni];
                    const int wcol = wn * 32 + ni * 16 + l15;
#pragma unroll
                    for (int j = 0; j < 4; j++)
                        Es[(mm * 16 + quad * 4 + j) * 68 + wcol] = a[j];
                }
        }
        __syncthreads();
#pragma unroll
        for (int it = 0; it < 2; it++) {
            const int tl = it * 16 + (tid >> 4);      // 0..31
            const int w4 = (tid & 15) * 4;            // 0..60
            const int t = tt * 128 + p * 32 + tl;
            const size_t a = (size_t)b * SB + (size_t)(t >> 4) * SC + (size_t)n * SN +
                             (size_t)(t & 15) * 128 + whalf * 64 + w4;
            float4 r4 = *(const float4*)&Es[tl * 68 + w4];
            const float4 buf = *(const float4*)(v + a);
            r4.x += buf.x; r4.y += buf.y; r4.z += buf.z; r4.w += buf.w;
            *(float4*)(out + a) = r4;
        }
    }
}

// ---------------------------------------------------------------------------
extern "C" void kernel_launch(void* const* d_in, const int* in_sizes, int n_in,
                              void* d_out, int out_size, void* d_ws, size_t ws_size,
                              hipStream_t stream) {
    const float* q = (const float*)d_in[0];
    const float* k = (const float*)d_in[1];
    const float* v = (const float*)d_in[2];
    float* out = (float*)d_out;

    float* ws = (float*)d_ws;
    float* nq2p = ws;                          // 20*4096 floats (sumsq partials)
    float* nk2p = ws + 81920;                  // 20*4096 floats
    __bf16* P = (__bf16*)(ws + 163840);        // 2 MB

    // d_out doubles as split-K scratch (20 * 2 MB bf16 = 40 MB <= 52 MB out),
    // fully overwritten by gemm2 afterwards.
    __bf16* Spart = (__bf16*)out;

    gemm1_kernel<<<dim3(G1BLOCKS), dim3(256), 0, stream>>>(q, k, Spart, nq2p, nk2p);
    softmax_kernel<<<dim3(64, 16), dim3(256), 0, stream>>>(Spart, nq2p, nk2p, P);
    gemm2_kernel<<<dim3(50, 2, 16), dim3(256), 0, stream>>>(P, v, out);
}

// Round 8
// 225.178 us; speedup vs baseline: 1.4867x; 1.0242x over previous
//
#include <hip/hip_runtime.h>
#include <math.h>

// Problem constants: token shape (b=16, c=16, n=25, h=16, w=128)
#define SB 819200   // batch stride = c*n*h*w
#define SC 51200    // c stride    = n*h*w
#define SN 2048     // n stride    = h*w
#define CH 256      // c*h  (t dim)
#define NW 3200     // n*w  (k dim of gemm1, s dim of gemm2)
#define NPARTS 10
#define PARTLEN 320         // 3200 / 10
#define SPART 1048576       // 16*256*256 bf16 ELEMENTS per split-K partial (2 MB)
#define G1BLOCKS 480        // 3 tiles * 10 parts * 16 b

typedef __bf16 bf16x8 __attribute__((ext_vector_type(8)));
typedef __bf16 bf16x4 __attribute__((ext_vector_type(4)));
typedef __bf16 bf16x2 __attribute__((ext_vector_type(2)));
typedef float  f32x4  __attribute__((ext_vector_type(4)));

__device__ __forceinline__ bf16x8 cvt8(float4 a, float4 b) {
    bf16x8 r;
    r[0] = (__bf16)a.x; r[1] = (__bf16)a.y; r[2] = (__bf16)a.z; r[3] = (__bf16)a.w;
    r[4] = (__bf16)b.x; r[5] = (__bf16)b.y; r[6] = (__bf16)b.z; r[7] = (__bf16)b.w;
    return r;
}

__device__ __forceinline__ float dot4(float4 a) {
    return a.x * a.x + a.y * a.y + a.z * a.z + a.w * a.w;
}

// ---------------------------------------------------------------------------
// Kernel 1: split-K bf16-MFMA score GEMM + fused row sum-of-squares.
// Spart[p][b][t][r] = sum_{k in part p} Q[t][k]*K[r][k], stored BF16.
// 128x128 tile, 4 waves of 64x64, causal 3-tile, LDS-free fragment loads
// (r4 structure: per lane a fragment = 8 contiguous k-floats of one row ->
// 2x dwordx4 direct from global; 1-step register ping-pong prefetch).
// ROUND-7/8: r6 closed the occupancy question (960 blocks, clean regs,
// still ~56 us / 1.85 TB/s) -> gemm1 is fetch-pattern-BW-bound. So cut
// BYTES instead: (1) XCD-aware grid -- the 3 causal tiles of one
// (b,part) share two 128-row panels; remap bx = xslot + 8*(tile +
// 3*cohort) so they land 8 apart = same XCD = duplicate panel reads
// become L2 hits (previously round-robin = worst case). (2) bf16 Spart
// halves the write (22 -> 11 MB) and softmax's read (42 -> 20 MB).
// (r7 bench was an infra failure; source unchanged for attribution.)
// ---------------------------------------------------------------------------
__global__ __launch_bounds__(256, 2) void gemm1_kernel(const float* __restrict__ q,
                                                       const float* __restrict__ k,
                                                       __bf16* __restrict__ Sp,
                                                       float* __restrict__ nq2p,
                                                       float* __restrict__ nk2p) {
    const int tid = threadIdx.x;
    const int lane = tid & 63;
    const int wave = tid >> 6;
    const int l15 = lane & 15;
    const int quad = lane >> 4;

    // XCD-aware decode: 3 tiles of a (part,b) group sit 8 apart -> same XCD
    const int bx = blockIdx.x;
    const int xslot = bx & 7;
    const int rest = bx >> 3;              // 0..59
    const int tile = rest % 3;             // 0:(0,0) 1:(1,0) 2:(1,1)
    const int cohort = rest / 3;           // 0..19
    const int group = cohort * 8 + xslot;  // 0..159 = part + 10*b
    const int part = group % NPARTS;
    const int b = group / NPARTS;
    const int tm = (tile + 1) >> 1;
    const int tn = tile >> 1;

    const int wm = wave >> 1;              // m 64-half
    const int wn = wave & 1;               // n 64-half

    const bool doQ = (tile != 2);
    const bool doK = (tile != 1);

    // per-fragment row pointers (include quad's k-octet offset)
    const float* qrow[4];
    const float* krow[4];
#pragma unroll
    for (int i = 0; i < 4; i++) {
        const int ta = tm * 128 + wm * 64 + i * 16 + l15;
        const int rb = tn * 128 + wn * 64 + i * 16 + l15;
        qrow[i] = q + (size_t)b * SB + (size_t)(ta >> 4) * SC + (size_t)(ta & 15) * 128 + quad * 8;
        krow[i] = k + (size_t)b * SB + (size_t)(rb >> 4) * SC + (size_t)(rb & 15) * 128 + quad * 8;
    }

    f32x4 acc[4][4] = {};
    bool live[4][4];
#pragma unroll
    for (int mi = 0; mi < 4; mi++)
#pragma unroll
        for (int ni = 0; ni < 4; ni++)
            live[mi][ni] = (tn * 128 + wn * 64 + ni * 16) <= (tm * 128 + wm * 64 + mi * 16);

    float sqA[4] = {0.f, 0.f, 0.f, 0.f};
    float sqB[4] = {0.f, 0.f, 0.f, 0.f};

    // two in-flight register sets (static names -> no scratch, rule #20)
    float4 aL0[4], aH0[4], bL0[4], bH0[4];
    float4 aL1[4], aH1[4], bL1[4], bH1[4];

    // k-offset for step j: cols kgb..kgb+31; (kgb&127)+quad*8+7 <= 127,
    // never crosses the SN boundary.
    auto loadstep = [&](int j, float4* aL, float4* aH, float4* bL, float4* bH) {
        const int kgb = part * PARTLEN + j * 32;
        const size_t koff = (size_t)(kgb >> 7) * SN + (kgb & 127);
#pragma unroll
        for (int i = 0; i < 4; i++) {
            aL[i] = *(const float4*)(qrow[i] + koff);
            aH[i] = *(const float4*)(qrow[i] + koff + 4);
        }
#pragma unroll
        for (int i = 0; i < 4; i++) {
            bL[i] = *(const float4*)(krow[i] + koff);
            bH[i] = *(const float4*)(krow[i] + koff + 4);
        }
    };

    auto compute = [&](const float4* aL, const float4* aH,
                       const float4* bL, const float4* bH) {
        bf16x8 af[4], bfr[4];
#pragma unroll
        for (int mi = 0; mi < 4; mi++) {
            af[mi] = cvt8(aL[mi], aH[mi]);
            if (wn == 0) sqA[mi] += dot4(aL[mi]) + dot4(aH[mi]);
        }
#pragma unroll
        for (int ni = 0; ni < 4; ni++) {
            bfr[ni] = cvt8(bL[ni], bH[ni]);
            if (wm == 0) sqB[ni] += dot4(bL[ni]) + dot4(bH[ni]);
        }
#pragma unroll
        for (int mi = 0; mi < 4; mi++)
#pragma unroll
            for (int ni = 0; ni < 4; ni++)
                if (live[mi][ni])
                    acc[mi][ni] = __builtin_amdgcn_mfma_f32_16x16x32_bf16(
                        af[mi], bfr[ni], acc[mi][ni], 0, 0, 0);
    };

    // 10 steps: S0/S1 ping-pong, 1-step lookahead
    loadstep(0, aL0, aH0, bL0, bH0);
#pragma unroll
    for (int jj = 0; jj < 4; jj++) {
        loadstep(2 * jj + 1, aL1, aH1, bL1, bH1);
        __builtin_amdgcn_sched_barrier(0);      // loads issued before compute
        compute(aL0, aH0, bL0, bH0);            // step 2jj
        loadstep(2 * jj + 2, aL0, aH0, bL0, bH0);
        __builtin_amdgcn_sched_barrier(0);
        compute(aL1, aH1, bL1, bH1);            // step 2jj+1
    }
    loadstep(9, aL1, aH1, bL1, bH1);
    __builtin_amdgcn_sched_barrier(0);
    compute(aL0, aH0, bL0, bH0);                // step 8
    compute(aL1, aH1, bL1, bH1);                // step 9

    // ---- Spart epilogue (bf16)
    __bf16* o = Sp + (size_t)part * SPART + (size_t)b * 65536;
#pragma unroll
    for (int mi = 0; mi < 4; mi++)
#pragma unroll
        for (int ni = 0; ni < 4; ni++) {
            if (!live[mi][ni]) continue;
            const int r = tn * 128 + wn * 64 + ni * 16 + l15;
#pragma unroll
            for (int j = 0; j < 4; j++) {
                const int t = tm * 128 + wm * 64 + mi * 16 + quad * 4 + j;
                o[(size_t)t * 256 + r] = (__bf16)acc[mi][ni][j];
            }
        }

    // ---- sumsq epilogue: reduce across the 4 quads (rows live in l15)
    if (wn == 0 && doQ) {
#pragma unroll
        for (int mi = 0; mi < 4; mi++) {
            float s = sqA[mi];
            s += __shfl_xor(s, 16, 64);
            s += __shfl_xor(s, 32, 64);
            if (lane < 16)
                nq2p[part * 4096 + b * 256 + tm * 128 + wm * 64 + mi * 16 + lane] = s;
        }
    }
    if (wm == 0 && doK) {
#pragma unroll
        for (int ni = 0; ni < 4; ni++) {
            float s = sqB[ni];
            s += __shfl_xor(s, 16, 64);
            s += __shfl_xor(s, 32, 64);
            if (lane < 16)
                nk2p[part * 4096 + b * 256 + tn * 128 + wn * 64 + ni * 16 + lane] = s;
        }
    }
}

// ---------------------------------------------------------------------------
// Kernel 2: sum bf16 split-K partials (10 x 2 MB = 20 MB read, was 40-42),
// finalize inverse norms, causal mask, softmax, write P as bf16.
// One wave per (b,t) row. Dead Spart regions are never read as live values
// (masking overwrites val[] by assignment).
// ---------------------------------------------------------------------------
__global__ __launch_bounds__(256) void softmax_kernel(const __bf16* __restrict__ Sp,
                                                      const float* __restrict__ nq2p,
                                                      const float* __restrict__ nk2p,
                                                      __bf16* __restrict__ P) {
    const int wave = threadIdx.x >> 6;
    const int lane = threadIdx.x & 63;
    const int t = blockIdx.x * 4 + wave;
    const int b = blockIdx.y;
    const size_t rowbase = ((size_t)b * 256 + t) * 256;
    const int r0 = lane * 4;

    float s0 = 0.f, s1 = 0.f, s2 = 0.f, s3 = 0.f;
#pragma unroll
    for (int p = 0; p < NPARTS; p++) {
        const bf16x4 x = *(const bf16x4*)(Sp + (size_t)p * SPART + rowbase + r0);
        s0 += (float)x[0]; s1 += (float)x[1]; s2 += (float)x[2]; s3 += (float)x[3];
    }
    float sq = 0.f;
#pragma unroll
    for (int p = 0; p < NPARTS; p++) sq += nq2p[p * 4096 + b * 256 + t];
    float4 sk = {0.f, 0.f, 0.f, 0.f};
#pragma unroll
    for (int p = 0; p < NPARTS; p++) {
        const float4 x = *(const float4*)(nk2p + p * 4096 + b * 256 + r0);
        sk.x += x.x; sk.y += x.y; sk.z += x.z; sk.w += x.w;
    }
    const float qn = 1.0f / fmaxf(sqrtf(sq), 1e-12f);
    float4 kn;
    kn.x = 1.0f / fmaxf(sqrtf(sk.x), 1e-12f);
    kn.y = 1.0f / fmaxf(sqrtf(sk.y), 1e-12f);
    kn.z = 1.0f / fmaxf(sqrtf(sk.z), 1e-12f);
    kn.w = 1.0f / fmaxf(sqrtf(sk.w), 1e-12f);

    float val[4] = {s0 * qn * kn.x, s1 * qn * kn.y,
                    s2 * qn * kn.z, s3 * qn * kn.w};
    float m = -1e30f;
#pragma unroll
    for (int j = 0; j < 4; j++) {
        if (r0 + j > t) val[j] = -1e30f;
        m = fmaxf(m, val[j]);
    }
#pragma unroll
    for (int off = 32; off; off >>= 1) m = fmaxf(m, __shfl_xor(m, off, 64));

    float e[4], sum = 0.f;
#pragma unroll
    for (int j = 0; j < 4; j++) {
        e[j] = (r0 + j <= t) ? expf(val[j] - m) : 0.f;
        sum += e[j];
    }
#pragma unroll
    for (int off = 32; off; off >>= 1) sum += __shfl_xor(sum, off, 64);

    const float inv = 1.0f / sum;
    bf16x4 o;
    o[0] = (__bf16)(e[0] * inv);
    o[1] = (__bf16)(e[1] * inv);
    o[2] = (__bf16)(e[2] * inv);
    o[3] = (__bf16)(e[3] * inv);
    *(bf16x4*)(P + rowbase + r0) = o;
}

// ---------------------------------------------------------------------------
// Kernel 3: O[t][s] = sum_r P[t][r]*V[r][s] + V[t][s], bf16 MFMA.
// Block = 128 t x 64 s (half of one n), K = 256 r in 4 chunks of 64.
// P A-fragments direct from global (L2-hot); V through LDS (transposed,
// XOR swizzle). ROUND-7/8: 1-D XCD-aware grid -- the two tt-tiles of one
// (nw,b) read the same 64 KB V-panel; remap so they sit 8 apart = same
// XCD = the second read is an L2 hit (was round-robin across XCDs).
// ---------------------------------------------------------------------------
__global__ __launch_bounds__(256, 4) void gemm2_kernel(const __bf16* __restrict__ P,
                                                       const float* __restrict__ v,
                                                       float* __restrict__ out) {
    __shared__ alignas(16) char smem[9216];
    __bf16* Vs = (__bf16*)smem;     // [64 s][72 r-stride]  (9216 B)
    float* Es = (float*)smem;       // [32][68] epilogue reuse (8704 B)

    const int tid = threadIdx.x;

    // XCD-aware decode: tt pair of a (nw,b) group sits 8 apart -> same XCD
    const int bx = blockIdx.x;             // 0..1599
    const int xslot = bx & 7;
    const int rest = bx >> 3;              // 0..199
    const int tt = rest & 1;               // t 128-half
    const int pc = rest >> 1;              // 0..99
    const int pair = pc * 8 + xslot;       // 0..799 = nw + 50*b
    const int nw = pair % 50;
    const int b = pair / 50;
    const int n = nw >> 1;
    const int whalf = nw & 1;

    const int lane = tid & 63;
    const int wave = tid >> 6;
    const int wm = wave >> 1;       // t 64-half within 128-tile
    const int wn = wave & 1;        // s 32-half within 64-tile
    const int l15 = lane & 15;
    const int quad = lane >> 4;

    // V staging coords: thread covers s-group vu*8..+7, row pair 2rp, 2rp+1
    const int vu = tid & 7;
    const int rp = tid >> 3;        // 0..31
    const float* vbase = v + (size_t)b * SB + (size_t)n * SN + whalf * 64;

    // P A-frag base: row = tt*128 + wm*64 + mi*16 + l15, col = kc*64+ks*32+quad*8
    const __bf16* Pbase = P + ((size_t)b * 256 + tt * 128 + wm * 64 + l15) * 256 + quad * 8;

    f32x4 acc[4][2] = {};

    for (int kc = 0; kc < 4; kc++) {
        // A fragments direct from global (issued early, L2-hot)
        bf16x8 af[4][2];
#pragma unroll
        for (int mi = 0; mi < 4; mi++)
#pragma unroll
            for (int ks = 0; ks < 2; ks++)
                af[mi][ks] = *(const bf16x8*)(Pbase + (size_t)mi * 16 * 256 + kc * 64 + ks * 32);

        // V loads: rows 2rp, 2rp+1 of this r-chunk, 8 floats each
        float vr0[8], vr1[8];
        {
            const int r0 = kc * 64 + 2 * rp;
            const int r1 = r0 + 1;
            const float* row0 = vbase + (size_t)(r0 >> 4) * SC + (size_t)(r0 & 15) * 128;
            const float* row1 = vbase + (size_t)(r1 >> 4) * SC + (size_t)(r1 & 15) * 128;
            *(float4*)&vr0[0] = *(const float4*)(row0 + vu * 8);
            *(float4*)&vr0[4] = *(const float4*)(row0 + vu * 8 + 4);
            *(float4*)&vr1[0] = *(const float4*)(row1 + vu * 8);
            *(float4*)&vr1[4] = *(const float4*)(row1 + vu * 8 + 4);
        }
        __syncthreads();   // prior Vs reads (or Es init) done
        {
            const int rl0 = 2 * rp;
#pragma unroll
            for (int sj = 0; sj < 8; sj++) {
                const int s = vu * 8 + sj;
                bf16x2 pr;
                pr[0] = (__bf16)vr0[sj];
                pr[1] = (__bf16)vr1[sj];
                *(bf16x2*)&Vs[s * 72 + (rl0 ^ (s & 0x38))] = pr;
            }
        }
        __syncthreads();
#pragma unroll
        for (int ks = 0; ks < 2; ks++) {
            bf16x8 bfr[2];
#pragma unroll
            for (int ni = 0; ni < 2; ni++) {
                const int s = wn * 32 + ni * 16 + l15;
                bfr[ni] = *(const bf16x8*)&Vs[s * 72 + ((ks * 32 + quad * 8) ^ (s & 0x38))];
            }
#pragma unroll
            for (int mi = 0; mi < 4; mi++)
#pragma unroll
                for (int ni = 0; ni < 2; ni++)
                    acc[mi][ni] = __builtin_amdgcn_mfma_f32_16x16x32_bf16(
                        af[mi][ks], bfr[ni], acc[mi][ni], 0, 0, 0);
        }
    }

    // ---- epilogue: 4 passes of 32 t-rows through Es[32][68], coalesced out
    for (int p = 0; p < 4; p++) {
        __syncthreads();   // prior Vs/Es reads done
        if (wm == (p >> 1)) {
            const int mibase = (p & 1) * 2;
#pragma unroll
            for (int mm = 0; mm < 2; mm++)
#pragma unroll
                for (int ni = 0; ni < 2; ni++) {
                    const f32x4 a = acc[mibase + mm][ni];
                    const int wcol = wn * 32 + ni * 16 + l15;
#pragma unroll
                    for (int j = 0; j < 4; j++)
                        Es[(mm * 16 + quad * 4 + j) * 68 + wcol] = a[j];
                }
        }
        __syncthreads();
#pragma unroll
        for (int it = 0; it < 2; it++) {
            const int tl = it * 16 + (tid >> 4);      // 0..31
            const int w4 = (tid & 15) * 4;            // 0..60
            const int t = tt * 128 + p * 32 + tl;
            const size_t a = (size_t)b * SB + (size_t)(t >> 4) * SC + (size_t)n * SN +
                             (size_t)(t & 15) * 128 + whalf * 64 + w4;
            float4 r4 = *(const float4*)&Es[tl * 68 + w4];
            const float4 buf = *(const float4*)(v + a);
            r4.x += buf.x; r4.y += buf.y; r4.z += buf.z; r4.w += buf.w;
            *(float4*)(out + a) = r4;
        }
    }
}

// ---------------------------------------------------------------------------
extern "C" void kernel_launch(void* const* d_in, const int* in_sizes, int n_in,
                              void* d_out, int out_size, void* d_ws, size_t ws_size,
                              hipStream_t stream) {
    const float* q = (const float*)d_in[0];
    const float* k = (const float*)d_in[1];
    const float* v = (const float*)d_in[2];
    float* out = (float*)d_out;

    float* ws = (float*)d_ws;
    float* nq2p = ws;                          // 10*4096 floats (sumsq partials)
    float* nk2p = ws + 40960;                  // 10*4096 floats
    __bf16* P = (__bf16*)(ws + 81920);         // 2 MB

    // d_out doubles as split-K scratch (10 * 2 MB bf16 = 20 MB <= 52 MB out),
    // fully overwritten by gemm2 afterwards.
    __bf16* Spart = (__bf16*)out;

    gemm1_kernel<<<dim3(G1BLOCKS), dim3(256), 0, stream>>>(q, k, Spart, nq2p, nk2p);
    softmax_kernel<<<dim3(64, 16), dim3(256), 0, stream>>>(Spart, nq2p, nk2p, P);
    gemm2_kernel<<<dim3(1600), dim3(256), 0, stream>>>(P, v, out);
}

// Round 9
// 223.788 us; speedup vs baseline: 1.4959x; 1.0062x over previous
//
#include <hip/hip_runtime.h>
#include <math.h>

// Problem constants: token shape (b=16, c=16, n=25, h=16, w=128)
#define SB 819200   // batch stride = c*n*h*w
#define SC 51200    // c stride    = n*h*w
#define SN 2048     // n stride    = h*w
#define CH 256      // c*h  (t dim)
#define NW 3200     // n*w  (k dim of gemm1, s dim of gemm2)
#define NPARTS 10
#define PARTLEN 320         // 3200 / 10
#define SPART 1048576       // 16*256*256 bf16 ELEMENTS per split-K partial (2 MB)
#define G1BLOCKS 480        // 3 tiles * 10 parts * 16 b

typedef __bf16 bf16x8 __attribute__((ext_vector_type(8)));
typedef __bf16 bf16x4 __attribute__((ext_vector_type(4)));
typedef __bf16 bf16x2 __attribute__((ext_vector_type(2)));
typedef float  f32x4  __attribute__((ext_vector_type(4)));

__device__ __forceinline__ bf16x8 cvt8(float4 a, float4 b) {
    bf16x8 r;
    r[0] = (__bf16)a.x; r[1] = (__bf16)a.y; r[2] = (__bf16)a.z; r[3] = (__bf16)a.w;
    r[4] = (__bf16)b.x; r[5] = (__bf16)b.y; r[6] = (__bf16)b.z; r[7] = (__bf16)b.w;
    return r;
}

__device__ __forceinline__ float dot4(float4 a) {
    return a.x * a.x + a.y * a.y + a.z * a.z + a.w * a.w;
}

// ---------------------------------------------------------------------------
// Kernel 1: split-K bf16-MFMA score GEMM + fused row sum-of-squares.
// UNCHANGED from round 8 (measured 53 us; four structural variants all land
// 53 +/- 4 -> treated as closed at its scattered-fetch issue-rate ceiling).
// ---------------------------------------------------------------------------
__global__ __launch_bounds__(256, 2) void gemm1_kernel(const float* __restrict__ q,
                                                       const float* __restrict__ k,
                                                       __bf16* __restrict__ Sp,
                                                       float* __restrict__ nq2p,
                                                       float* __restrict__ nk2p) {
    const int tid = threadIdx.x;
    const int lane = tid & 63;
    const int wave = tid >> 6;
    const int l15 = lane & 15;
    const int quad = lane >> 4;

    // XCD-aware decode: 3 tiles of a (part,b) group sit 8 apart -> same XCD
    const int bx = blockIdx.x;
    const int xslot = bx & 7;
    const int rest = bx >> 3;              // 0..59
    const int tile = rest % 3;             // 0:(0,0) 1:(1,0) 2:(1,1)
    const int cohort = rest / 3;           // 0..19
    const int group = cohort * 8 + xslot;  // 0..159 = part + 10*b
    const int part = group % NPARTS;
    const int b = group / NPARTS;
    const int tm = (tile + 1) >> 1;
    const int tn = tile >> 1;

    const int wm = wave >> 1;              // m 64-half
    const int wn = wave & 1;               // n 64-half

    const bool doQ = (tile != 2);
    const bool doK = (tile != 1);

    // per-fragment row pointers (include quad's k-octet offset)
    const float* qrow[4];
    const float* krow[4];
#pragma unroll
    for (int i = 0; i < 4; i++) {
        const int ta = tm * 128 + wm * 64 + i * 16 + l15;
        const int rb = tn * 128 + wn * 64 + i * 16 + l15;
        qrow[i] = q + (size_t)b * SB + (size_t)(ta >> 4) * SC + (size_t)(ta & 15) * 128 + quad * 8;
        krow[i] = k + (size_t)b * SB + (size_t)(rb >> 4) * SC + (size_t)(rb & 15) * 128 + quad * 8;
    }

    f32x4 acc[4][4] = {};
    bool live[4][4];
#pragma unroll
    for (int mi = 0; mi < 4; mi++)
#pragma unroll
        for (int ni = 0; ni < 4; ni++)
            live[mi][ni] = (tn * 128 + wn * 64 + ni * 16) <= (tm * 128 + wm * 64 + mi * 16);

    float sqA[4] = {0.f, 0.f, 0.f, 0.f};
    float sqB[4] = {0.f, 0.f, 0.f, 0.f};

    // two in-flight register sets (static names -> no scratch, rule #20)
    float4 aL0[4], aH0[4], bL0[4], bH0[4];
    float4 aL1[4], aH1[4], bL1[4], bH1[4];

    auto loadstep = [&](int j, float4* aL, float4* aH, float4* bL, float4* bH) {
        const int kgb = part * PARTLEN + j * 32;
        const size_t koff = (size_t)(kgb >> 7) * SN + (kgb & 127);
#pragma unroll
        for (int i = 0; i < 4; i++) {
            aL[i] = *(const float4*)(qrow[i] + koff);
            aH[i] = *(const float4*)(qrow[i] + koff + 4);
        }
#pragma unroll
        for (int i = 0; i < 4; i++) {
            bL[i] = *(const float4*)(krow[i] + koff);
            bH[i] = *(const float4*)(krow[i] + koff + 4);
        }
    };

    auto compute = [&](const float4* aL, const float4* aH,
                       const float4* bL, const float4* bH) {
        bf16x8 af[4], bfr[4];
#pragma unroll
        for (int mi = 0; mi < 4; mi++) {
            af[mi] = cvt8(aL[mi], aH[mi]);
            if (wn == 0) sqA[mi] += dot4(aL[mi]) + dot4(aH[mi]);
        }
#pragma unroll
        for (int ni = 0; ni < 4; ni++) {
            bfr[ni] = cvt8(bL[ni], bH[ni]);
            if (wm == 0) sqB[ni] += dot4(bL[ni]) + dot4(bH[ni]);
        }
#pragma unroll
        for (int mi = 0; mi < 4; mi++)
#pragma unroll
            for (int ni = 0; ni < 4; ni++)
                if (live[mi][ni])
                    acc[mi][ni] = __builtin_amdgcn_mfma_f32_16x16x32_bf16(
                        af[mi], bfr[ni], acc[mi][ni], 0, 0, 0);
    };

    // 10 steps: S0/S1 ping-pong, 1-step lookahead
    loadstep(0, aL0, aH0, bL0, bH0);
#pragma unroll
    for (int jj = 0; jj < 4; jj++) {
        loadstep(2 * jj + 1, aL1, aH1, bL1, bH1);
        __builtin_amdgcn_sched_barrier(0);      // loads issued before compute
        compute(aL0, aH0, bL0, bH0);            // step 2jj
        loadstep(2 * jj + 2, aL0, aH0, bL0, bH0);
        __builtin_amdgcn_sched_barrier(0);
        compute(aL1, aH1, bL1, bH1);            // step 2jj+1
    }
    loadstep(9, aL1, aH1, bL1, bH1);
    __builtin_amdgcn_sched_barrier(0);
    compute(aL0, aH0, bL0, bH0);                // step 8
    compute(aL1, aH1, bL1, bH1);                // step 9

    // ---- Spart epilogue (bf16)
    __bf16* o = Sp + (size_t)part * SPART + (size_t)b * 65536;
#pragma unroll
    for (int mi = 0; mi < 4; mi++)
#pragma unroll
        for (int ni = 0; ni < 4; ni++) {
            if (!live[mi][ni]) continue;
            const int r = tn * 128 + wn * 64 + ni * 16 + l15;
#pragma unroll
            for (int j = 0; j < 4; j++) {
                const int t = tm * 128 + wm * 64 + mi * 16 + quad * 4 + j;
                o[(size_t)t * 256 + r] = (__bf16)acc[mi][ni][j];
            }
        }

    // ---- sumsq epilogue: reduce across the 4 quads (rows live in l15)
    if (wn == 0 && doQ) {
#pragma unroll
        for (int mi = 0; mi < 4; mi++) {
            float s = sqA[mi];
            s += __shfl_xor(s, 16, 64);
            s += __shfl_xor(s, 32, 64);
            if (lane < 16)
                nq2p[part * 4096 + b * 256 + tm * 128 + wm * 64 + mi * 16 + lane] = s;
        }
    }
    if (wm == 0 && doK) {
#pragma unroll
        for (int ni = 0; ni < 4; ni++) {
            float s = sqB[ni];
            s += __shfl_xor(s, 16, 64);
            s += __shfl_xor(s, 32, 64);
            if (lane < 16)
                nk2p[part * 4096 + b * 256 + tn * 128 + wn * 64 + ni * 16 + lane] = s;
        }
    }
}

// ---------------------------------------------------------------------------
// Kernel 2 (ROUND-9 REWRITE): sum bf16 split-K partials, inverse norms,
// causal mask, softmax, write P bf16 -- with MAX per-instruction efficiency.
// Evidence: r3's 16B-coalesced fp32 softmax (42 MB) beat r8's 8B bf16x4
// softmax (20 MB) by ~6-9 us e2e -> this pass is instruction/latency-bound,
// not byte-bound. New shape: each wave handles TWO rows with 32 lanes each;
// every Spart load is bf16x8 = 16 B/lane, and one load instruction covers
// 2 rows x 512 B fully contiguous (was: 64 scattered 8 B accesses).
// Block = 4 waves = 8 rows; grid (32, 16) = 512 blocks.
// Reductions stay within each 32-lane half (xor offsets 16..1).
// ---------------------------------------------------------------------------
__global__ __launch_bounds__(256) void softmax_kernel(const __bf16* __restrict__ Sp,
                                                      const float* __restrict__ nq2p,
                                                      const float* __restrict__ nk2p,
                                                      __bf16* __restrict__ P) {
    const int wave = threadIdx.x >> 6;
    const int lane = threadIdx.x & 63;
    const int hl = lane >> 5;              // which row of the wave's pair
    const int sl = lane & 31;              // 0..31, covers r0 = sl*8
    const int t = blockIdx.x * 8 + wave * 2 + hl;
    const int b = blockIdx.y;
    const size_t rowbase = ((size_t)b * 256 + t) * 256;
    const int r0 = sl * 8;

    // sum the 10 partials: 10x bf16x8 (16B/lane, 2x512B contiguous per instr)
    float s[8] = {0.f, 0.f, 0.f, 0.f, 0.f, 0.f, 0.f, 0.f};
#pragma unroll
    for (int p = 0; p < NPARTS; p++) {
        const bf16x8 x = *(const bf16x8*)(Sp + (size_t)p * SPART + rowbase + r0);
#pragma unroll
        for (int j = 0; j < 8; j++) s[j] += (float)x[j];
    }

    // norms
    float sq = 0.f;
#pragma unroll
    for (int p = 0; p < NPARTS; p++) sq += nq2p[p * 4096 + b * 256 + t];
    float sk[8] = {0.f, 0.f, 0.f, 0.f, 0.f, 0.f, 0.f, 0.f};
#pragma unroll
    for (int p = 0; p < NPARTS; p++) {
        const float4 x0 = *(const float4*)(nk2p + p * 4096 + b * 256 + r0);
        const float4 x1 = *(const float4*)(nk2p + p * 4096 + b * 256 + r0 + 4);
        sk[0] += x0.x; sk[1] += x0.y; sk[2] += x0.z; sk[3] += x0.w;
        sk[4] += x1.x; sk[5] += x1.y; sk[6] += x1.z; sk[7] += x1.w;
    }
    const float qn = 1.0f / fmaxf(sqrtf(sq), 1e-12f);

    float val[8];
    float m = -1e30f;
#pragma unroll
    for (int j = 0; j < 8; j++) {
        const float kn = 1.0f / fmaxf(sqrtf(sk[j]), 1e-12f);
        val[j] = s[j] * qn * kn;
        if (r0 + j > t) val[j] = -1e30f;
        m = fmaxf(m, val[j]);
    }
    // max over the 32-lane half (offsets <= 16 stay within the half)
#pragma unroll
    for (int off = 16; off; off >>= 1) m = fmaxf(m, __shfl_xor(m, off, 64));

    float e[8], sum = 0.f;
#pragma unroll
    for (int j = 0; j < 8; j++) {
        e[j] = (r0 + j <= t) ? expf(val[j] - m) : 0.f;
        sum += e[j];
    }
#pragma unroll
    for (int off = 16; off; off >>= 1) sum += __shfl_xor(sum, off, 64);

    const float inv = 1.0f / sum;
    bf16x8 o;
#pragma unroll
    for (int j = 0; j < 8; j++) o[j] = (__bf16)(e[j] * inv);
    *(bf16x8*)(P + rowbase + r0) = o;   // 16B/lane, 2x512B contiguous
}

// ---------------------------------------------------------------------------
// Kernel 3: O[t][s] = sum_r P[t][r]*V[r][s] + V[t][s], bf16 MFMA.
// UNCHANGED from round 8 (1-D XCD grid; measured within noise of 3-D).
// ---------------------------------------------------------------------------
__global__ __launch_bounds__(256, 4) void gemm2_kernel(const __bf16* __restrict__ P,
                                                       const float* __restrict__ v,
                                                       float* __restrict__ out) {
    __shared__ alignas(16) char smem[9216];
    __bf16* Vs = (__bf16*)smem;     // [64 s][72 r-stride]  (9216 B)
    float* Es = (float*)smem;       // [32][68] epilogue reuse (8704 B)

    const int tid = threadIdx.x;

    // XCD-aware decode: tt pair of a (nw,b) group sits 8 apart -> same XCD
    const int bx = blockIdx.x;             // 0..1599
    const int xslot = bx & 7;
    const int rest = bx >> 3;              // 0..199
    const int tt = rest & 1;               // t 128-half
    const int pc = rest >> 1;              // 0..99
    const int pair = pc * 8 + xslot;       // 0..799 = nw + 50*b
    const int nw = pair % 50;
    const int b = pair / 50;
    const int n = nw >> 1;
    const int whalf = nw & 1;

    const int lane = tid & 63;
    const int wave = tid >> 6;
    const int wm = wave >> 1;       // t 64-half within 128-tile
    const int wn = wave & 1;        // s 32-half within 64-tile
    const int l15 = lane & 15;
    const int quad = lane >> 4;

    // V staging coords: thread covers s-group vu*8..+7, row pair 2rp, 2rp+1
    const int vu = tid & 7;
    const int rp = tid >> 3;        // 0..31
    const float* vbase = v + (size_t)b * SB + (size_t)n * SN + whalf * 64;

    // P A-frag base: row = tt*128 + wm*64 + mi*16 + l15, col = kc*64+ks*32+quad*8
    const __bf16* Pbase = P + ((size_t)b * 256 + tt * 128 + wm * 64 + l15) * 256 + quad * 8;

    f32x4 acc[4][2] = {};

    for (int kc = 0; kc < 4; kc++) {
        // A fragments direct from global (issued early, L2-hot)
        bf16x8 af[4][2];
#pragma unroll
        for (int mi = 0; mi < 4; mi++)
#pragma unroll
            for (int ks = 0; ks < 2; ks++)
                af[mi][ks] = *(const bf16x8*)(Pbase + (size_t)mi * 16 * 256 + kc * 64 + ks * 32);

        // V loads: rows 2rp, 2rp+1 of this r-chunk, 8 floats each
        float vr0[8], vr1[8];
        {
            const int r0 = kc * 64 + 2 * rp;
            const int r1 = r0 + 1;
            const float* row0 = vbase + (size_t)(r0 >> 4) * SC + (size_t)(r0 & 15) * 128;
            const float* row1 = vbase + (size_t)(r1 >> 4) * SC + (size_t)(r1 & 15) * 128;
            *(float4*)&vr0[0] = *(const float4*)(row0 + vu * 8);
            *(float4*)&vr0[4] = *(const float4*)(row0 + vu * 8 + 4);
            *(float4*)&vr1[0] = *(const float4*)(row1 + vu * 8);
            *(float4*)&vr1[4] = *(const float4*)(row1 + vu * 8 + 4);
        }
        __syncthreads();   // prior Vs reads (or Es init) done
        {
            const int rl0 = 2 * rp;
#pragma unroll
            for (int sj = 0; sj < 8; sj++) {
                const int s = vu * 8 + sj;
                bf16x2 pr;
                pr[0] = (__bf16)vr0[sj];
                pr[1] = (__bf16)vr1[sj];
                *(bf16x2*)&Vs[s * 72 + (rl0 ^ (s & 0x38))] = pr;
            }
        }
        __syncthreads();
#pragma unroll
        for (int ks = 0; ks < 2; ks++) {
            bf16x8 bfr[2];
#pragma unroll
            for (int ni = 0; ni < 2; ni++) {
                const int s = wn * 32 + ni * 16 + l15;
                bfr[ni] = *(const bf16x8*)&Vs[s * 72 + ((ks * 32 + quad * 8) ^ (s & 0x38))];
            }
#pragma unroll
            for (int mi = 0; mi < 4; mi++)
#pragma unroll
                for (int ni = 0; ni < 2; ni++)
                    acc[mi][ni] = __builtin_amdgcn_mfma_f32_16x16x32_bf16(
                        af[mi][ks], bfr[ni], acc[mi][ni], 0, 0, 0);
        }
    }

    // ---- epilogue: 4 passes of 32 t-rows through Es[32][68], coalesced out
    for (int p = 0; p < 4; p++) {
        __syncthreads();   // prior Vs/Es reads done
        if (wm == (p >> 1)) {
            const int mibase = (p & 1) * 2;
#pragma unroll
            for (int mm = 0; mm < 2; mm++)
#pragma unroll
                for (int ni = 0; ni < 2; ni++) {
                    const f32x4 a = acc[mibase + mm][ni];
                    const int wcol = wn * 32 + ni * 16 + l15;
#pragma unroll
                    for (int j = 0; j < 4; j++)
                        Es[(mm * 16 + quad * 4 + j) * 68 + wcol] = a[j];
                }
        }
        __syncthreads();
#pragma unroll
        for (int it = 0; it < 2; it++) {
            const int tl = it * 16 + (tid >> 4);      // 0..31
            const int w4 = (tid & 15) * 4;            // 0..60
            const int t = tt * 128 + p * 32 + tl;
            const size_t a = (size_t)b * SB + (size_t)(t >> 4) * SC + (size_t)n * SN +
                             (size_t)(t & 15) * 128 + whalf * 64 + w4;
            float4 r4 = *(const float4*)&Es[tl * 68 + w4];
            const float4 buf = *(const float4*)(v + a);
            r4.x += buf.x; r4.y += buf.y; r4.z += buf.z; r4.w += buf.w;
            *(float4*)(out + a) = r4;
        }
    }
}

// ---------------------------------------------------------------------------
extern "C" void kernel_launch(void* const* d_in, const int* in_sizes, int n_in,
                              void* d_out, int out_size, void* d_ws, size_t ws_size,
                              hipStream_t stream) {
    const float* q = (const float*)d_in[0];
    const float* k = (const float*)d_in[1];
    const float* v = (const float*)d_in[2];
    float* out = (float*)d_out;

    float* ws = (float*)d_ws;
    float* nq2p = ws;                          // 10*4096 floats (sumsq partials)
    float* nk2p = ws + 40960;                  // 10*4096 floats
    __bf16* P = (__bf16*)(ws + 81920);         // 2 MB

    // d_out doubles as split-K scratch (10 * 2 MB bf16 = 20 MB <= 52 MB out),
    // fully overwritten by gemm2 afterwards.
    __bf16* Spart = (__bf16*)out;

    gemm1_kernel<<<dim3(G1BLOCKS), dim3(256), 0, stream>>>(q, k, Spart, nq2p, nk2p);
    softmax_kernel<<<dim3(32, 16), dim3(256), 0, stream>>>(Spart, nq2p, nk2p, P);
    gemm2_kernel<<<dim3(1600), dim3(256), 0, stream>>>(P, v, out);
}